// Round 10
// baseline (1883.275 us; speedup 1.0000x reference)
//
#include <hip/hip_runtime.h>

typedef unsigned short u16;
typedef __attribute__((ext_vector_type(8))) short short8;
typedef __attribute__((ext_vector_type(4))) float f32x4;

#define T_TOKENS 4096
#define DMODEL   768
#define DFF      3072
#define NEXP     8
#define NVOCAB   32000

__device__ __forceinline__ u16 f2bf(float f) {
  unsigned u = __float_as_uint(f);
  u += 0x7FFFu + ((u >> 16) & 1u);
  return (u16)(u >> 16);
}
__device__ __forceinline__ float bf2f(u16 b) {
  return __uint_as_float(((unsigned)b) << 16);
}

__device__ __forceinline__ void async_load16(const void* g, void* lds) {
  __builtin_amdgcn_global_load_lds((const __attribute__((address_space(1))) void*)g,
                                   (__attribute__((address_space(3))) void*)lds, 16, 0, 0);
}

#define SBAR() __builtin_amdgcn_s_barrier()
#define VMCNT(n) asm volatile("s_waitcnt vmcnt(" #n ")")
#define LGKM(n)  asm volatile("s_waitcnt lgkmcnt(" #n ")")
#define SCHEDB() __builtin_amdgcn_sched_barrier(0)

// ---------------- embed + router + top2 list build ----------------
__global__ __launch_bounds__(256) void k_embed_router(
    const int* __restrict__ x, const float* __restrict__ emb,
    const float* __restrict__ gw, const float* __restrict__ gb,
    u16* __restrict__ tbf, int* __restrict__ counts,
    int* __restrict__ tlist, float* __restrict__ wlist)
{
  __shared__ float partial[4][NEXP];
  const int t = blockIdx.x;
  const int tok = x[t];
  const float* er = emb + (size_t)tok * DMODEL;
  float p[NEXP];
#pragma unroll
  for (int e = 0; e < NEXP; ++e) p[e] = 0.f;
#pragma unroll
  for (int i = 0; i < 3; ++i) {
    const int d = threadIdx.x + i * 256;
    const float v = er[d];
    tbf[(size_t)t * DMODEL + d] = f2bf(v);
#pragma unroll
    for (int e = 0; e < NEXP; ++e) p[e] += v * gw[d * NEXP + e];
  }
#pragma unroll
  for (int e = 0; e < NEXP; ++e)
#pragma unroll
    for (int m = 32; m >= 1; m >>= 1) p[e] += __shfl_xor(p[e], m);
  const int lane = threadIdx.x & 63, wv = threadIdx.x >> 6;
  if (lane == 0)
    for (int e = 0; e < NEXP; ++e) partial[wv][e] = p[e];
  __syncthreads();
  if (threadIdx.x == 0) {
    float l[NEXP];
    for (int e = 0; e < NEXP; ++e)
      l[e] = partial[0][e] + partial[1][e] + partial[2][e] + partial[3][e] + gb[e];
    int i0 = 0;
    for (int e = 1; e < NEXP; ++e) if (l[e] > l[i0]) i0 = e;   // ties: first (jax)
    int i1 = -1;
    for (int e = 0; e < NEXP; ++e) { if (e == i0) continue; if (i1 < 0 || l[e] > l[i1]) i1 = e; }
    const float w0 = 1.f / (1.f + expf(l[i1] - l[i0]));
    int p0 = atomicAdd(&counts[0 * NEXP + i0], 1);
    tlist[(0 * NEXP + i0) * T_TOKENS + p0] = t;
    wlist[(0 * NEXP + i0) * T_TOKENS + p0] = w0;
    int p1 = atomicAdd(&counts[1 * NEXP + i1], 1);
    tlist[(1 * NEXP + i1) * T_TOKENS + p1] = t;
    wlist[(1 * NEXP + i1) * T_TOKENS + p1] = 1.f - w0;
  }
}

// ---------------- transpose + fp32->bf16 convert ----------------
__global__ __launch_bounds__(256) void k_transpose_cvt(
    const float* __restrict__ src, u16* __restrict__ dst, int R, int C)
{
  __shared__ float tile[32][33];
  const float* s = src + (size_t)blockIdx.z * R * C;
  u16* d = dst + (size_t)blockIdx.z * R * C;
  const int tx = threadIdx.x & 31, ty = threadIdx.x >> 5;
  const int c = blockIdx.x * 32 + tx;
#pragma unroll
  for (int i = 0; i < 4; ++i) {
    const int r = blockIdx.y * 32 + ty + i * 8;
    tile[ty + i * 8][tx] = s[(size_t)r * C + c];
  }
  __syncthreads();
  const int rr = blockIdx.y * 32 + tx;
#pragma unroll
  for (int i = 0; i < 4; ++i) {
    const int cc = blockIdx.x * 32 + ty + i * 8;
    d[(size_t)cc * R + rr] = f2bf(tile[tx][ty + i * 8]);
  }
}

// ---------------- sparse MoE FFN: one slot (gathered 128^2 GEMM) ----------------
template <int SLOT1>
__global__ __launch_bounds__(256) void k_ffn_slot(
    const u16* __restrict__ tbf, const u16* __restrict__ BT,
    const float* __restrict__ eb, const int* __restrict__ counts,
    const int* __restrict__ tlist, const float* __restrict__ wlist,
    u16* __restrict__ moe)
{
  const int e = blockIdx.z;
  const int cnt = counts[SLOT1 * NEXP + e];
  const int mb = blockIdx.y;
  if (mb * 128 >= cnt) return;
  const int base = (SLOT1 * NEXP + e) * T_TOKENS + mb * 128;
  const int lim = cnt - mb * 128;

  __shared__ u16 aT[128 * 64];
  __shared__ u16 bT[128 * 64];
  const int tid = threadIdx.x;
  const int wave = tid >> 6, lane = tid & 63;
  const int wm = wave >> 1, wn = wave & 1;
  const int kg = lane >> 4, fr = lane & 15;
  const int n0 = blockIdx.x * 128;
  const u16* Be = BT + (size_t)e * DFF * DMODEL;

  int tokm[4];
#pragma unroll
  for (int it = 0; it < 4; ++it) {
    const int m = (it * 256 + tid) >> 3;
    tokm[it] = tlist[base + (m < lim ? m : lim - 1)];
  }

  f32x4 acc[4][4] = {};
  for (int ks = 0; ks < DMODEL / 64; ++ks) {
    __syncthreads();
    const int kb = ks * 64;
#pragma unroll
    for (int it = 0; it < 4; ++it) {
      const int c = it * 256 + tid;
      const int m = c >> 3;
      const int slot = (c & 7) ^ (m & 7);
      async_load16(tbf + (size_t)tokm[it] * DMODEL + kb + slot * 8,
                   &aT[(it * 256 + wave * 64) * 8]);
      async_load16(Be + (size_t)(n0 + m) * DMODEL + kb + slot * 8,
                   &bT[(it * 256 + wave * 64) * 8]);
    }
    __syncthreads();
#pragma unroll
    for (int kk = 0; kk < 2; ++kk) {
      short8 af[4], bf[4];
#pragma unroll
      for (int i = 0; i < 4; ++i) {
        const int am = wm * 64 + i * 16 + fr;
        const int kc = kk * 4 + kg;
        af[i] = *(const short8*)&aT[(am * 8 + (kc ^ (am & 7))) * 8];
        const int bn = wn * 64 + i * 16 + fr;
        bf[i] = *(const short8*)&bT[(bn * 8 + (kc ^ (bn & 7))) * 8];
      }
#pragma unroll
      for (int i = 0; i < 4; ++i)
#pragma unroll
        for (int j = 0; j < 4; ++j)
          acc[i][j] = __builtin_amdgcn_mfma_f32_16x16x32_bf16(af[i], bf[j], acc[i][j], 0, 0, 0);
    }
  }

  int trow[4][4]; float wrow[4][4];
#pragma unroll
  for (int i = 0; i < 4; ++i)
#pragma unroll
    for (int r = 0; r < 4; ++r) {
      const int row = wm * 64 + i * 16 + kg * 4 + r;
      if (row < lim) { trow[i][r] = tlist[base + row]; wrow[i][r] = wlist[base + row]; }
      else trow[i][r] = -1;
    }
#pragma unroll
  for (int j = 0; j < 4; ++j) {
    const int col = n0 + wn * 64 + j * 16 + fr;
    const float b = eb[e * DFF + col];
#pragma unroll
    for (int i = 0; i < 4; ++i)
#pragma unroll
      for (int r = 0; r < 4; ++r) {
        if (trow[i][r] < 0) continue;
        float v = acc[i][j][r] + b;
        v = v > 0.f ? v : 0.f;
        v *= wrow[i][r];
        u16* dst = &moe[(size_t)trow[i][r] * DFF + col];
        if (SLOT1) v += bf2f(*dst);
        *dst = f2bf(v);
      }
  }
}

// ---------------- head GEMM: 128^2 tile, 2 blocks/CU, pipelined 4-phase ----------------
// Mechanism under test: cross-block TLP. LDS 64KB -> 2 blocks/CU; while one
// block's waves sit in barrier/waitcnt, the co-resident block's waves feed the
// same SIMDs' MFMA pipes. Phase structure = R6 cross-phase register prefetch.
// Phases split by (kk, n-pair). Per wave (4 waves, 2x2 of 64x64): af[4][2],
// bf[4][2]; 8 MFMA/phase.
//   P1: pre bf[23][0](2);          stage B(t+1)h1; MFMA af[*][0]xbf[01][0]
//   P2: pre af[*][1](4)+bf[01][1](2);               MFMA af[*][0]xbf[23][0]
//   P3: pre bf[23][1](2); LGKM(2); stage A(t+2)h0; MFMA af[*][1]xbf[01][1]; VMCNT(2)
//   P4: pre af'(t+1)[0](4)+bf'(t+1)[01][0](2); LGKM(6); stage A(t+2)h1+B(t+2)h0;
//       MFMA af[*][1]xbf[23][1]
// vmcnt ledger (2 loads/slot): entering P1(t) outstanding = {A(t+1)h0(P3,t-1),
// A(t+1)h1, B(t+1)h0(P4,t-1)} = 6; P1 +2, P3 +2 -> 10; VMCNT(2)@P3-end keeps
// {A(t+2)h0}, drains A(t+1)h1/B(t+1)h0/B(t+1)h1 -> P4-pre reads safe.
// Write-after-read: LGKM(2)@P3 drains P2-pre (A rows being restaged);
// LGKM(6)@P4 drains P3-pre (B-h0 rows being restaged). Tail: t==NT-2 ->
// VMCNT(0)@P3-end; t==NT-1 -> no pre'/stages, LGKM(0)@P4.
__device__ __forceinline__ short8 frag(const u16* buf, int row, int kc) {
  return *(const short8*)(buf + (row * 8 + (kc ^ (row & 7))) * 8);
}

__global__ __launch_bounds__(256) void k_head(
    const u16* __restrict__ A, const u16* __restrict__ BT,
    const float* __restrict__ bias, float* __restrict__ C)
{
  __shared__ u16 aL[2][128 * 64];
  __shared__ u16 bL[2][128 * 64];
  const int tid = threadIdx.x;
  const int lane = tid & 63, wave = tid >> 6;
  const int wm = wave >> 1, wn = wave & 1;         // 2 x 2 wave grid
  const int kg = lane >> 4, fr = lane & 15;
  const int wg = (int)blockIdx.x;
  const int swz = (wg & 7) * 1000 + (wg >> 3);     // bijective XCD swizzle (8000=8*1000)
  const int m0 = (swz & 31) * 128;                 // m-fastest: 32 blocks share B panel
  const int n0 = (swz >> 5) * 128;
  const int K = DFF, NT = K / 64;                  // 48 tiles

  // hoisted staging descriptors: 2 loads/thread per half-tile slot
  size_t gAo[2], gBo[2]; int lOf[2];
#pragma unroll
  for (int i = 0; i < 2; ++i) {
    const int c = i * 256 + tid, rl = c >> 3, s = c & 7;  // rl 0..63 within half
    const int gs = s ^ (rl & 7);                   // pre-swizzled global slot
    gAo[i] = (size_t)(m0 + rl) * K + gs * 8;
    gBo[i] = (size_t)(n0 + rl) * K + gs * 8;
    lOf[i] = (rl * 8 + s) * 8;                     // linear LDS dest (lane*16B)
  }
  auto stageA = [&](int kb, u16* buf, int h) {
#pragma unroll
    for (int i = 0; i < 2; ++i)
      async_load16(A + gAo[i] + (size_t)(h * 64) * K + kb, buf + lOf[i] + h * 4096);
  };
  auto stageB = [&](int kb, u16* buf, int h) {
#pragma unroll
    for (int i = 0; i < 2; ++i)
      async_load16(BT + gBo[i] + (size_t)(h * 64) * K + kb, buf + lOf[i] + h * 4096);
  };

  f32x4 acc[4][4] = {};
  short8 af[4][2], bf[4][2];

  // prologue: tile0 full + tile1 {Ah0,Ah1,Bh0}; drain tile0 (VMCNT(6)); preload
  stageA(0, aL[0], 0); stageA(0, aL[0], 1);
  stageB(0, bL[0], 0); stageB(0, bL[0], 1);
  stageA(64, aL[1], 0); stageA(64, aL[1], 1); stageB(64, bL[1], 0);
  VMCNT(6);
  SCHEDB();
  SBAR();
#pragma unroll
  for (int mi = 0; mi < 4; ++mi)
    af[mi][0] = frag(aL[0], wm * 64 + mi * 16 + fr, kg);
#pragma unroll
  for (int nj = 0; nj < 2; ++nj)
    bf[nj][0] = frag(bL[0], wn * 64 + nj * 16 + fr, kg);

  for (int t = 0; t < NT; ++t) {
    const int cur = t & 1;
    const u16* a_ = aL[cur];
    const u16* b_ = bL[cur];
    const u16* an = aL[cur ^ 1];
    const u16* bn = bL[cur ^ 1];
    u16* aw = aL[cur];                  // A(t+2) target
    u16* bw = bL[cur];                  // B(t+2) target
    u16* bwn = bL[cur ^ 1];             // B(t+1) target
    const int kb1 = (t + 1) * 64, kb2 = (t + 2) * 64;

    // ---- P1 ----
#pragma unroll
    for (int nj = 2; nj < 4; ++nj)
      bf[nj][0] = frag(b_, wn * 64 + nj * 16 + fr, kg);
    if (t + 1 < NT) stageB(kb1, bwn, 1);
    __builtin_amdgcn_s_setprio(1);
#pragma unroll
    for (int mi = 0; mi < 4; ++mi)
#pragma unroll
      for (int nj = 0; nj < 2; ++nj)
        acc[mi][nj] = __builtin_amdgcn_mfma_f32_16x16x32_bf16(af[mi][0], bf[nj][0], acc[mi][nj], 0, 0, 0);
    __builtin_amdgcn_s_setprio(0);
    SBAR();

    // ---- P2 ----
#pragma unroll
    for (int mi = 0; mi < 4; ++mi)
      af[mi][1] = frag(a_, wm * 64 + mi * 16 + fr, 4 + kg);
#pragma unroll
    for (int nj = 0; nj < 2; ++nj)
      bf[nj][1] = frag(b_, wn * 64 + nj * 16 + fr, 4 + kg);
    __builtin_amdgcn_s_setprio(1);
#pragma unroll
    for (int mi = 0; mi < 4; ++mi)
#pragma unroll
      for (int nj = 2; nj < 4; ++nj)
        acc[mi][nj] = __builtin_amdgcn_mfma_f32_16x16x32_bf16(af[mi][0], bf[nj][0], acc[mi][nj], 0, 0, 0);
    __builtin_amdgcn_s_setprio(0);
    SBAR();

    // ---- P3 ----
#pragma unroll
    for (int nj = 2; nj < 4; ++nj)
      bf[nj][1] = frag(b_, wn * 64 + nj * 16 + fr, 4 + kg);
    LGKM(2);               // drain P2-pre reads (A rows / B-low rows) before restage
    SCHEDB();
    if (t + 2 < NT) stageA(kb2, aw, 0);
    __builtin_amdgcn_s_setprio(1);
#pragma unroll
    for (int mi = 0; mi < 4; ++mi)
#pragma unroll
      for (int nj = 0; nj < 2; ++nj)
        acc[mi][nj] = __builtin_amdgcn_mfma_f32_16x16x32_bf16(af[mi][1], bf[nj][1], acc[mi][nj], 0, 0, 0);
    __builtin_amdgcn_s_setprio(0);
    if (t < NT - 2) { VMCNT(2); } else { VMCNT(0); }
    SCHEDB();
    SBAR();

    // ---- P4 ----
    if (t + 1 < NT) {
#pragma unroll
      for (int mi = 0; mi < 4; ++mi)
        af[mi][0] = frag(an, wm * 64 + mi * 16 + fr, kg);
#pragma unroll
      for (int nj = 0; nj < 2; ++nj)
        bf[nj][0] = frag(bn, wn * 64 + nj * 16 + fr, kg);
      LGKM(6);             // drain P3-pre reads (B rows being restaged)
    } else {
      LGKM(0);
    }
    SCHEDB();
    if (t + 2 < NT) { stageA(kb2, aw, 1); stageB(kb2, bw, 0); }
    __builtin_amdgcn_s_setprio(1);
#pragma unroll
    for (int mi = 0; mi < 4; ++mi)
#pragma unroll
      for (int nj = 2; nj < 4; ++nj)
        acc[mi][nj] = __builtin_amdgcn_mfma_f32_16x16x32_bf16(af[mi][1], bf[nj][1], acc[mi][nj], 0, 0, 0);
    __builtin_amdgcn_s_setprio(0);
    SBAR();
  }

  // epilogue: non-temporal stores
#pragma unroll
  for (int nj = 0; nj < 4; ++nj) {
    const int col = n0 + wn * 64 + nj * 16 + fr;
    const float b = bias[col];
#pragma unroll
    for (int mi = 0; mi < 4; ++mi) {
      const int row = m0 + wm * 64 + mi * 16 + kg * 4;
#pragma unroll
      for (int r = 0; r < 4; ++r)
        __builtin_nontemporal_store(acc[mi][nj][r] + b,
                                    &C[(size_t)(row + r) * NVOCAB + col]);
    }
  }
}

extern "C" void kernel_launch(void* const* d_in, const int* in_sizes, int n_in,
                              void* d_out, int out_size, void* d_ws, size_t ws_size,
                              hipStream_t stream) {
  const int*   x     = (const int*)d_in[0];
  const float* emb   = (const float*)d_in[1];
  const float* gw    = (const float*)d_in[2];
  const float* gb    = (const float*)d_in[3];
  const float* expw  = (const float*)d_in[4];
  const float* expb  = (const float*)d_in[5];
  const float* headw = (const float*)d_in[6];
  const float* headb = (const float*)d_in[7];
  float* out = (float*)d_out;

  char* ws = (char*)d_ws;
  size_t off = 0;
  auto alloc = [&](size_t bytes) { size_t r = off; off += (bytes + 255) & ~(size_t)255; return r; };
  u16*   tbf    = (u16*)(ws + alloc((size_t)T_TOKENS * DMODEL * 2));
  int*   counts = (int*)(ws + alloc(2 * NEXP * 4));
  int*   tlist  = (int*)(ws + alloc((size_t)2 * NEXP * T_TOKENS * 4));
  float* wlist  = (float*)(ws + alloc((size_t)2 * NEXP * T_TOKENS * 4));
  u16*   expwT  = (u16*)(ws + alloc((size_t)NEXP * DFF * DMODEL * 2));
  u16*   headwT = (u16*)(ws + alloc((size_t)NVOCAB * DFF * 2));
  u16*   moe    = (u16*)(ws + alloc((size_t)T_TOKENS * DFF * 2));

  hipMemsetAsync(counts, 0, 2 * NEXP * 4, stream);
  k_embed_router<<<T_TOKENS, 256, 0, stream>>>(x, emb, gw, gb, tbf, counts, tlist, wlist);
  k_transpose_cvt<<<dim3(DFF / 32, DMODEL / 32, NEXP), 256, 0, stream>>>(expw, expwT, DMODEL, DFF);
  k_transpose_cvt<<<dim3(NVOCAB / 32, DFF / 32, 1), 256, 0, stream>>>(headw, headwT, DFF, NVOCAB);
  k_ffn_slot<0><<<dim3(DFF / 128, T_TOKENS / 128, NEXP), 256, 0, stream>>>(
      tbf, expwT, expb, counts, tlist, wlist, moe);
  k_ffn_slot<1><<<dim3(DFF / 128, T_TOKENS / 128, NEXP), 256, 0, stream>>>(
      tbf, expwT, expb, counts, tlist, wlist, moe);
  k_head<<<(T_TOKENS / 128) * (NVOCAB / 128), 256, 0, stream>>>(moe, headwT, headb, out);
}

// Round 11
// 1245.981 us; speedup vs baseline: 1.5115x; 1.5115x over previous
//
#include <hip/hip_runtime.h>

typedef unsigned short u16;
typedef __attribute__((ext_vector_type(8))) short short8;
typedef __attribute__((ext_vector_type(4))) float f32x4;

#define T_TOKENS 4096
#define DMODEL   768
#define DFF      3072
#define NEXP     8
#define NVOCAB   32000

__device__ __forceinline__ u16 f2bf(float f) {
  unsigned u = __float_as_uint(f);
  u += 0x7FFFu + ((u >> 16) & 1u);
  return (u16)(u >> 16);
}
__device__ __forceinline__ float bf2f(u16 b) {
  return __uint_as_float(((unsigned)b) << 16);
}

__device__ __forceinline__ void async_load16(const void* g, void* lds) {
  __builtin_amdgcn_global_load_lds((const __attribute__((address_space(1))) void*)g,
                                   (__attribute__((address_space(3))) void*)lds, 16, 0, 0);
}

#define SBAR() __builtin_amdgcn_s_barrier()
#define VMCNT(n) asm volatile("s_waitcnt vmcnt(" #n ")")

// ---------------- embed + router + top2 list build ----------------
__global__ __launch_bounds__(256) void k_embed_router(
    const int* __restrict__ x, const float* __restrict__ emb,
    const float* __restrict__ gw, const float* __restrict__ gb,
    u16* __restrict__ tbf, int* __restrict__ counts,
    int* __restrict__ tlist, float* __restrict__ wlist)
{
  __shared__ float partial[4][NEXP];
  const int t = blockIdx.x;
  const int tok = x[t];
  const float* er = emb + (size_t)tok * DMODEL;
  float p[NEXP];
#pragma unroll
  for (int e = 0; e < NEXP; ++e) p[e] = 0.f;
#pragma unroll
  for (int i = 0; i < 3; ++i) {
    const int d = threadIdx.x + i * 256;
    const float v = er[d];
    tbf[(size_t)t * DMODEL + d] = f2bf(v);
#pragma unroll
    for (int e = 0; e < NEXP; ++e) p[e] += v * gw[d * NEXP + e];
  }
#pragma unroll
  for (int e = 0; e < NEXP; ++e)
#pragma unroll
    for (int m = 32; m >= 1; m >>= 1) p[e] += __shfl_xor(p[e], m);
  const int lane = threadIdx.x & 63, wv = threadIdx.x >> 6;
  if (lane == 0)
    for (int e = 0; e < NEXP; ++e) partial[wv][e] = p[e];
  __syncthreads();
  if (threadIdx.x == 0) {
    float l[NEXP];
    for (int e = 0; e < NEXP; ++e)
      l[e] = partial[0][e] + partial[1][e] + partial[2][e] + partial[3][e] + gb[e];
    int i0 = 0;
    for (int e = 1; e < NEXP; ++e) if (l[e] > l[i0]) i0 = e;   // ties: first (jax)
    int i1 = -1;
    for (int e = 0; e < NEXP; ++e) { if (e == i0) continue; if (i1 < 0 || l[e] > l[i1]) i1 = e; }
    const float w0 = 1.f / (1.f + expf(l[i1] - l[i0]));
    // slot 0 -> expert i0 weight w0 ; slot 1 -> expert i1 weight 1-w0
    int p0 = atomicAdd(&counts[0 * NEXP + i0], 1);
    tlist[(0 * NEXP + i0) * T_TOKENS + p0] = t;
    wlist[(0 * NEXP + i0) * T_TOKENS + p0] = w0;
    int p1 = atomicAdd(&counts[1 * NEXP + i1], 1);
    tlist[(1 * NEXP + i1) * T_TOKENS + p1] = t;
    wlist[(1 * NEXP + i1) * T_TOKENS + p1] = 1.f - w0;
  }
}

// ---------------- transpose + fp32->bf16 convert ----------------
__global__ __launch_bounds__(256) void k_transpose_cvt(
    const float* __restrict__ src, u16* __restrict__ dst, int R, int C)
{
  __shared__ float tile[32][33];
  const float* s = src + (size_t)blockIdx.z * R * C;
  u16* d = dst + (size_t)blockIdx.z * R * C;
  const int tx = threadIdx.x & 31, ty = threadIdx.x >> 5;
  const int c = blockIdx.x * 32 + tx;
#pragma unroll
  for (int i = 0; i < 4; ++i) {
    const int r = blockIdx.y * 32 + ty + i * 8;
    tile[ty + i * 8][tx] = s[(size_t)r * C + c];
  }
  __syncthreads();
  const int rr = blockIdx.y * 32 + tx;
#pragma unroll
  for (int i = 0; i < 4; ++i) {
    const int cc = blockIdx.x * 32 + ty + i * 8;
    d[(size_t)cc * R + rr] = f2bf(tile[tx][ty + i * 8]);
  }
}

// ---------------- sparse MoE FFN: one slot (gathered 128^2 GEMM) ----------------
// Grid: x=fblock(24), y=mblock(32), z=expert(8). Early-exit if mb*128 >= cnt.
// A rows gathered via tlist (per-lane global src for global_load_lds is legal).
// SLOT1 reads-adds-writes moe (unique writer per (t,col) within a kernel;
// slot0 covers every token exactly once so moe is fully initialized).
template <int SLOT1>
__global__ __launch_bounds__(256) void k_ffn_slot(
    const u16* __restrict__ tbf, const u16* __restrict__ BT,
    const float* __restrict__ eb, const int* __restrict__ counts,
    const int* __restrict__ tlist, const float* __restrict__ wlist,
    u16* __restrict__ moe)
{
  const int e = blockIdx.z;
  const int cnt = counts[SLOT1 * NEXP + e];
  const int mb = blockIdx.y;
  if (mb * 128 >= cnt) return;
  const int base = (SLOT1 * NEXP + e) * T_TOKENS + mb * 128;
  const int lim = cnt - mb * 128;                 // valid rows in this tile (1..128)

  __shared__ u16 aT[128 * 64];
  __shared__ u16 bT[128 * 64];
  const int tid = threadIdx.x;
  const int wave = tid >> 6, lane = tid & 63;
  const int wm = wave >> 1, wn = wave & 1;
  const int kg = lane >> 4, fr = lane & 15;
  const int n0 = blockIdx.x * 128;
  const u16* Be = BT + (size_t)e * DFF * DMODEL;

  // staging token ids (4 rows per thread), clamped to last valid entry
  int tokm[4];
#pragma unroll
  for (int it = 0; it < 4; ++it) {
    const int m = (it * 256 + tid) >> 3;
    tokm[it] = tlist[base + (m < lim ? m : lim - 1)];
  }

  f32x4 acc[4][4] = {};
  for (int ks = 0; ks < DMODEL / 64; ++ks) {
    __syncthreads();
    const int kb = ks * 64;
#pragma unroll
    for (int it = 0; it < 4; ++it) {
      const int c = it * 256 + tid;
      const int m = c >> 3;
      const int slot = (c & 7) ^ (m & 7);
      async_load16(tbf + (size_t)tokm[it] * DMODEL + kb + slot * 8,
                   &aT[(it * 256 + wave * 64) * 8]);
      async_load16(Be + (size_t)(n0 + m) * DMODEL + kb + slot * 8,
                   &bT[(it * 256 + wave * 64) * 8]);
    }
    __syncthreads();
#pragma unroll
    for (int kk = 0; kk < 2; ++kk) {
      short8 af[4], bf[4];
#pragma unroll
      for (int i = 0; i < 4; ++i) {
        const int am = wm * 64 + i * 16 + fr;
        const int kc = kk * 4 + kg;
        af[i] = *(const short8*)&aT[(am * 8 + (kc ^ (am & 7))) * 8];
        const int bn = wn * 64 + i * 16 + fr;
        bf[i] = *(const short8*)&bT[(bn * 8 + (kc ^ (bn & 7))) * 8];
      }
#pragma unroll
      for (int i = 0; i < 4; ++i)
#pragma unroll
        for (int j = 0; j < 4; ++j)
          acc[i][j] = __builtin_amdgcn_mfma_f32_16x16x32_bf16(af[i], bf[j], acc[i][j], 0, 0, 0);
    }
  }

  // epilogue: per-row token/weight lookup, relu+bias, weighted (add for slot1)
  int trow[4][4]; float wrow[4][4];
#pragma unroll
  for (int i = 0; i < 4; ++i)
#pragma unroll
    for (int r = 0; r < 4; ++r) {
      const int row = wm * 64 + i * 16 + kg * 4 + r;
      if (row < lim) { trow[i][r] = tlist[base + row]; wrow[i][r] = wlist[base + row]; }
      else trow[i][r] = -1;
    }
#pragma unroll
  for (int j = 0; j < 4; ++j) {
    const int col = n0 + wn * 64 + j * 16 + fr;
    const float b = eb[e * DFF + col];
#pragma unroll
    for (int i = 0; i < 4; ++i)
#pragma unroll
      for (int r = 0; r < 4; ++r) {
        if (trow[i][r] < 0) continue;
        float v = acc[i][j][r] + b;
        v = v > 0.f ? v : 0.f;
        v *= wrow[i][r];
        u16* dst = &moe[(size_t)trow[i][r] * DFF + col];
        if (SLOT1) v += bf2f(*dst);
        *dst = f2bf(v);
      }
  }
}

// ---------------- head GEMM: 256^2 tile, 16x16x32, pipelined 4-phase (R6 best) ----------------
__device__ __forceinline__ short8 frag(const u16* buf, int row, int kc) {
  return *(const short8*)(buf + (row * 8 + (kc ^ (row & 7))) * 8);
}

__global__ __launch_bounds__(512, 2) void k_head(
    const u16* __restrict__ A, const u16* __restrict__ BT,
    const float* __restrict__ bias, float* __restrict__ C)
{
  __shared__ u16 aL[2][256 * 64];
  __shared__ u16 bL[2][256 * 64];
  const int tid = threadIdx.x;
  const int lane = tid & 63, wave = tid >> 6;
  const int wm = wave >> 2, wn = wave & 3;         // 2 x 4 wave grid
  const int kg = lane >> 4, fr = lane & 15;
  const int wg = (int)blockIdx.x;
  const int swz = (wg & 7) * 250 + (wg >> 3);      // bijective XCD swizzle (2000=8*250)
  const int m0 = (swz & 15) * 256;
  const int n0 = (swz >> 4) * 256;
  const int K = DFF, NT = K / 64;                  // 48 tiles

  size_t gAo[2], gBo[2]; int lAo[2], lBo[2];
#pragma unroll
  for (int i = 0; i < 2; ++i) {
    const int c = i * 512 + tid, rl = c >> 3, s = c & 7;
    const int rA = (rl & 63) + ((rl >> 6) << 7);
    const int gsA = s ^ (rA & 7);
    gAo[i] = (size_t)(m0 + rA) * K + gsA * 8;
    lAo[i] = rA * 64 + s * 8;
    const int rB = (rl & 31) + ((rl >> 5) << 6);
    const int gsB = s ^ (rB & 7);
    gBo[i] = (size_t)(n0 + rB) * K + gsB * 8;
    lBo[i] = rB * 64 + s * 8;
  }
  auto stageA = [&](int kb, u16* buf, int h) {
#pragma unroll
    for (int i = 0; i < 2; ++i)
      async_load16(A + gAo[i] + (size_t)(h * 64) * K + kb, buf + lAo[i] + h * 4096);
  };
  auto stageB = [&](int kb, u16* buf, int h) {
#pragma unroll
    for (int i = 0; i < 2; ++i)
      async_load16(BT + gBo[i] + (size_t)(h * 32) * K + kb, buf + lBo[i] + h * 2048);
  };

  f32x4 acc[8][4] = {};
  short8 af0[4][2], af1[4][2], bfl[2][2], bfh[2][2];

  stageA(0, aL[0], 0); stageA(0, aL[0], 1);
  stageB(0, bL[0], 0); stageB(0, bL[0], 1);
  stageA(64, aL[1], 0); stageB(64, bL[1], 0); stageA(64, aL[1], 1);
  VMCNT(6);
  __builtin_amdgcn_sched_barrier(0);
  SBAR();
#pragma unroll
  for (int mi = 0; mi < 4; ++mi)
#pragma unroll
    for (int kk = 0; kk < 2; ++kk)
      af0[mi][kk] = frag(aL[0], wm * 128 + mi * 16 + fr, kk * 4 + kg);
#pragma unroll
  for (int ni = 0; ni < 2; ++ni)
#pragma unroll
    for (int kk = 0; kk < 2; ++kk)
      bfl[ni][kk] = frag(bL[0], wn * 64 + ni * 16 + fr, kk * 4 + kg);

  for (int t = 0; t < NT; ++t) {
    const int cur = t & 1;
    const u16* a_ = aL[cur];
    const u16* b_ = bL[cur];
    u16* aw = aL[cur];
    u16* bw = bL[cur];
    const u16* an = aL[cur ^ 1];
    const u16* bn = bL[cur ^ 1];
    const int kb1 = (t + 1) * 64, kb2 = (t + 2) * 64;

    // ---- P1: pre = bfh(t) + stage bL[t+1]h1; MFMA af0 x bfl ----
#pragma unroll
    for (int ni = 0; ni < 2; ++ni)
#pragma unroll
      for (int kk = 0; kk < 2; ++kk)
        bfh[ni][kk] = frag(b_, wn * 64 + 32 + ni * 16 + fr, kk * 4 + kg);
    if (t + 1 < NT) stageB(kb1, bL[cur ^ 1], 1);
    __builtin_amdgcn_s_setprio(1);
#pragma unroll
    for (int mi = 0; mi < 4; ++mi)
#pragma unroll
      for (int ni = 0; ni < 2; ++ni)
#pragma unroll
        for (int kk = 0; kk < 2; ++kk)
          acc[mi][ni] = __builtin_amdgcn_mfma_f32_16x16x32_bf16(af0[mi][kk], bfl[ni][kk], acc[mi][ni], 0, 0, 0);
    __builtin_amdgcn_s_setprio(0);
    SBAR();

    // ---- P2: pre = af1(t) + stage aL[t+2]h0; MFMA af0 x bfh ----
#pragma unroll
    for (int mi = 0; mi < 4; ++mi)
#pragma unroll
      for (int kk = 0; kk < 2; ++kk)
        af1[mi][kk] = frag(a_, wm * 128 + 64 + mi * 16 + fr, kk * 4 + kg);
    if (t + 2 < NT) stageA(kb2, aw, 0);
    __builtin_amdgcn_s_setprio(1);
#pragma unroll
    for (int mi = 0; mi < 4; ++mi)
#pragma unroll
      for (int ni = 0; ni < 2; ++ni)
#pragma unroll
        for (int kk = 0; kk < 2; ++kk)
          acc[mi][ni + 2] = __builtin_amdgcn_mfma_f32_16x16x32_bf16(af0[mi][kk], bfh[ni][kk], acc[mi][ni + 2], 0, 0, 0);
    __builtin_amdgcn_s_setprio(0);
    if (t < NT - 2) { VMCNT(8); } else if (t == NT - 2) { VMCNT(6); }
    __builtin_amdgcn_sched_barrier(0);
    SBAR();

    // ---- P3: pre = af0(t+1) + stage bL[t+2]h0; MFMA af1 x bfl ----
    if (t + 1 < NT) {
#pragma unroll
      for (int mi = 0; mi < 4; ++mi)
#pragma unroll
        for (int kk = 0; kk < 2; ++kk)
          af0[mi][kk] = frag(an, wm * 128 + mi * 16 + fr, kk * 4 + kg);
    }
    if (t + 2 < NT) stageB(kb2, bw, 0);
    __builtin_amdgcn_s_setprio(1);
#pragma unroll
    for (int mi = 0; mi < 4; ++mi)
#pragma unroll
      for (int ni = 0; ni < 2; ++ni)
#pragma unroll
        for (int kk = 0; kk < 2; ++kk)
          acc[mi + 4][ni] = __builtin_amdgcn_mfma_f32_16x16x32_bf16(af1[mi][kk], bfl[ni][kk], acc[mi + 4][ni], 0, 0, 0);
    __builtin_amdgcn_s_setprio(0);
    if (t < NT - 2) { VMCNT(8); } else if (t == NT - 2) { VMCNT(4); }
    __builtin_amdgcn_sched_barrier(0);
    SBAR();

    // ---- P4: pre = bfl(t+1) + stage aL[t+2]h1; MFMA af1 x bfh ----
    if (t + 1 < NT) {
#pragma unroll
      for (int ni = 0; ni < 2; ++ni)
#pragma unroll
        for (int kk = 0; kk < 2; ++kk)
          bfl[ni][kk] = frag(bn, wn * 64 + ni * 16 + fr, kk * 4 + kg);
    }
    if (t + 2 < NT) stageA(kb2, aw, 1);
    __builtin_amdgcn_s_setprio(1);
#pragma unroll
    for (int mi = 0; mi < 4; ++mi)
#pragma unroll
      for (int ni = 0; ni < 2; ++ni)
#pragma unroll
        for (int kk = 0; kk < 2; ++kk)
          acc[mi + 4][ni + 2] = __builtin_amdgcn_mfma_f32_16x16x32_bf16(af1[mi][kk], bfh[ni][kk], acc[mi + 4][ni + 2], 0, 0, 0);
    __builtin_amdgcn_s_setprio(0);
    if (t < NT - 2) { VMCNT(6); } else if (t == NT - 2) { VMCNT(0); }
    __builtin_amdgcn_sched_barrier(0);
    SBAR();
  }

  // epilogue: non-temporal stores
#pragma unroll
  for (int ni = 0; ni < 4; ++ni) {
    const int col = n0 + wn * 64 + ni * 16 + fr;
    const float b = bias[col];
#pragma unroll
    for (int mi = 0; mi < 8; ++mi) {
      const int row = m0 + wm * 128 + (mi >> 2) * 64 + (mi & 3) * 16 + kg * 4;
#pragma unroll
      for (int r = 0; r < 4; ++r)
        __builtin_nontemporal_store(acc[mi][ni][r] + b,
                                    &C[(size_t)(row + r) * NVOCAB + col]);
    }
  }
}

extern "C" void kernel_launch(void* const* d_in, const int* in_sizes, int n_in,
                              void* d_out, int out_size, void* d_ws, size_t ws_size,
                              hipStream_t stream) {
  const int*   x     = (const int*)d_in[0];
  const float* emb   = (const float*)d_in[1];
  const float* gw    = (const float*)d_in[2];
  const float* gb    = (const float*)d_in[3];
  const float* expw  = (const float*)d_in[4];
  const float* expb  = (const float*)d_in[5];
  const float* headw = (const float*)d_in[6];
  const float* headb = (const float*)d_in[7];
  float* out = (float*)d_out;

  char* ws = (char*)d_ws;
  size_t off = 0;
  auto alloc = [&](size_t bytes) { size_t r = off; off += (bytes + 255) & ~(size_t)255; return r; };
  u16*   tbf    = (u16*)(ws + alloc((size_t)T_TOKENS * DMODEL * 2));
  int*   counts = (int*)(ws + alloc(2 * NEXP * 4));
  int*   tlist  = (int*)(ws + alloc((size_t)2 * NEXP * T_TOKENS * 4));
  float* wlist  = (float*)(ws + alloc((size_t)2 * NEXP * T_TOKENS * 4));
  u16*   expwT  = (u16*)(ws + alloc((size_t)NEXP * DFF * DMODEL * 2));
  u16*   headwT = (u16*)(ws + alloc((size_t)NVOCAB * DFF * 2));
  u16*   moe    = (u16*)(ws + alloc((size_t)T_TOKENS * DFF * 2));

  hipMemsetAsync(counts, 0, 2 * NEXP * 4, stream);
  k_embed_router<<<T_TOKENS, 256, 0, stream>>>(x, emb, gw, gb, tbf, counts, tlist, wlist);
  k_transpose_cvt<<<dim3(DFF / 32, DMODEL / 32, NEXP), 256, 0, stream>>>(expw, expwT, DMODEL, DFF);
  k_transpose_cvt<<<dim3(NVOCAB / 32, DFF / 32, 1), 256, 0, stream>>>(headw, headwT, DFF, NVOCAB);
  k_ffn_slot<0><<<dim3(DFF / 128, T_TOKENS / 128, NEXP), 256, 0, stream>>>(
      tbf, expwT, expb, counts, tlist, wlist, moe);
  k_ffn_slot<1><<<dim3(DFF / 128, T_TOKENS / 128, NEXP), 256, 0, stream>>>(
      tbf, expwT, expb, counts, tlist, wlist, moe);
  k_head<<<(T_TOKENS / 256) * (NVOCAB / 256), 512, 0, stream>>>(moe, headwT, headb, out);
}

// Round 12
// 1181.148 us; speedup vs baseline: 1.5944x; 1.0549x over previous
//
#include <hip/hip_runtime.h>

typedef unsigned short u16;
typedef __attribute__((ext_vector_type(8))) short short8;
typedef __attribute__((ext_vector_type(4))) float f32x4;

#define T_TOKENS 4096
#define DMODEL   768
#define DFF      3072
#define NEXP     8
#define NVOCAB   32000

__device__ __forceinline__ u16 f2bf(float f) {
  unsigned u = __float_as_uint(f);
  u += 0x7FFFu + ((u >> 16) & 1u);
  return (u16)(u >> 16);
}
__device__ __forceinline__ float bf2f(u16 b) {
  return __uint_as_float(((unsigned)b) << 16);
}

__device__ __forceinline__ void async_load16(const void* g, void* lds) {
  __builtin_amdgcn_global_load_lds((const __attribute__((address_space(1))) void*)g,
                                   (__attribute__((address_space(3))) void*)lds, 16, 0, 0);
}

#define SBAR() __builtin_amdgcn_s_barrier()
#define VMCNT(n) asm volatile("s_waitcnt vmcnt(" #n ")")
#define SCHEDB() __builtin_amdgcn_sched_barrier(0)

// ---------------- embed + router + top2 list build ----------------
__global__ __launch_bounds__(256) void k_embed_router(
    const int* __restrict__ x, const float* __restrict__ emb,
    const float* __restrict__ gw, const float* __restrict__ gb,
    u16* __restrict__ tbf, int* __restrict__ counts,
    int* __restrict__ tlist, float* __restrict__ wlist)
{
  __shared__ float partial[4][NEXP];
  const int t = blockIdx.x;
  const int tok = x[t];
  const float* er = emb + (size_t)tok * DMODEL;
  float p[NEXP];
#pragma unroll
  for (int e = 0; e < NEXP; ++e) p[e] = 0.f;
#pragma unroll
  for (int i = 0; i < 3; ++i) {
    const int d = threadIdx.x + i * 256;
    const float v = er[d];
    tbf[(size_t)t * DMODEL + d] = f2bf(v);
#pragma unroll
    for (int e = 0; e < NEXP; ++e) p[e] += v * gw[d * NEXP + e];
  }
#pragma unroll
  for (int e = 0; e < NEXP; ++e)
#pragma unroll
    for (int m = 32; m >= 1; m >>= 1) p[e] += __shfl_xor(p[e], m);
  const int lane = threadIdx.x & 63, wv = threadIdx.x >> 6;
  if (lane == 0)
    for (int e = 0; e < NEXP; ++e) partial[wv][e] = p[e];
  __syncthreads();
  if (threadIdx.x == 0) {
    float l[NEXP];
    for (int e = 0; e < NEXP; ++e)
      l[e] = partial[0][e] + partial[1][e] + partial[2][e] + partial[3][e] + gb[e];
    int i0 = 0;
    for (int e = 1; e < NEXP; ++e) if (l[e] > l[i0]) i0 = e;   // ties: first (jax)
    int i1 = -1;
    for (int e = 0; e < NEXP; ++e) { if (e == i0) continue; if (i1 < 0 || l[e] > l[i1]) i1 = e; }
    const float w0 = 1.f / (1.f + expf(l[i1] - l[i0]));
    int p0 = atomicAdd(&counts[0 * NEXP + i0], 1);
    tlist[(0 * NEXP + i0) * T_TOKENS + p0] = t;
    wlist[(0 * NEXP + i0) * T_TOKENS + p0] = w0;
    int p1 = atomicAdd(&counts[1 * NEXP + i1], 1);
    tlist[(1 * NEXP + i1) * T_TOKENS + p1] = t;
    wlist[(1 * NEXP + i1) * T_TOKENS + p1] = 1.f - w0;
  }
}

// ---------------- transpose + fp32->bf16 convert ----------------
__global__ __launch_bounds__(256) void k_transpose_cvt(
    const float* __restrict__ src, u16* __restrict__ dst, int R, int C)
{
  __shared__ float tile[32][33];
  const float* s = src + (size_t)blockIdx.z * R * C;
  u16* d = dst + (size_t)blockIdx.z * R * C;
  const int tx = threadIdx.x & 31, ty = threadIdx.x >> 5;
  const int c = blockIdx.x * 32 + tx;
#pragma unroll
  for (int i = 0; i < 4; ++i) {
    const int r = blockIdx.y * 32 + ty + i * 8;
    tile[ty + i * 8][tx] = s[(size_t)r * C + c];
  }
  __syncthreads();
  const int rr = blockIdx.y * 32 + tx;
#pragma unroll
  for (int i = 0; i < 4; ++i) {
    const int cc = blockIdx.x * 32 + ty + i * 8;
    d[(size_t)cc * R + rr] = f2bf(tile[tx][ty + i * 8]);
  }
}

// ---------------- sparse MoE FFN: one slot (gathered 128^2 GEMM) ----------------
template <int SLOT1>
__global__ __launch_bounds__(256) void k_ffn_slot(
    const u16* __restrict__ tbf, const u16* __restrict__ BT,
    const float* __restrict__ eb, const int* __restrict__ counts,
    const int* __restrict__ tlist, const float* __restrict__ wlist,
    u16* __restrict__ moe)
{
  const int e = blockIdx.z;
  const int cnt = counts[SLOT1 * NEXP + e];
  const int mb = blockIdx.y;
  if (mb * 128 >= cnt) return;
  const int base = (SLOT1 * NEXP + e) * T_TOKENS + mb * 128;
  const int lim = cnt - mb * 128;

  __shared__ u16 aT[128 * 64];
  __shared__ u16 bT[128 * 64];
  const int tid = threadIdx.x;
  const int wave = tid >> 6, lane = tid & 63;
  const int wm = wave >> 1, wn = wave & 1;
  const int kg = lane >> 4, fr = lane & 15;
  const int n0 = blockIdx.x * 128;
  const u16* Be = BT + (size_t)e * DFF * DMODEL;

  int tokm[4];
#pragma unroll
  for (int it = 0; it < 4; ++it) {
    const int m = (it * 256 + tid) >> 3;
    tokm[it] = tlist[base + (m < lim ? m : lim - 1)];
  }

  f32x4 acc[4][4] = {};
  for (int ks = 0; ks < DMODEL / 64; ++ks) {
    __syncthreads();
    const int kb = ks * 64;
#pragma unroll
    for (int it = 0; it < 4; ++it) {
      const int c = it * 256 + tid;
      const int m = c >> 3;
      const int slot = (c & 7) ^ (m & 7);
      async_load16(tbf + (size_t)tokm[it] * DMODEL + kb + slot * 8,
                   &aT[(it * 256 + wave * 64) * 8]);
      async_load16(Be + (size_t)(n0 + m) * DMODEL + kb + slot * 8,
                   &bT[(it * 256 + wave * 64) * 8]);
    }
    __syncthreads();
#pragma unroll
    for (int kk = 0; kk < 2; ++kk) {
      short8 af[4], bf[4];
#pragma unroll
      for (int i = 0; i < 4; ++i) {
        const int am = wm * 64 + i * 16 + fr;
        const int kc = kk * 4 + kg;
        af[i] = *(const short8*)&aT[(am * 8 + (kc ^ (am & 7))) * 8];
        const int bn = wn * 64 + i * 16 + fr;
        bf[i] = *(const short8*)&bT[(bn * 8 + (kc ^ (bn & 7))) * 8];
      }
#pragma unroll
      for (int i = 0; i < 4; ++i)
#pragma unroll
        for (int j = 0; j < 4; ++j)
          acc[i][j] = __builtin_amdgcn_mfma_f32_16x16x32_bf16(af[i], bf[j], acc[i][j], 0, 0, 0);
    }
  }

  int trow[4][4]; float wrow[4][4];
#pragma unroll
  for (int i = 0; i < 4; ++i)
#pragma unroll
    for (int r = 0; r < 4; ++r) {
      const int row = wm * 64 + i * 16 + kg * 4 + r;
      if (row < lim) { trow[i][r] = tlist[base + row]; wrow[i][r] = wlist[base + row]; }
      else trow[i][r] = -1;
    }
#pragma unroll
  for (int j = 0; j < 4; ++j) {
    const int col = n0 + wn * 64 + j * 16 + fr;
    const float b = eb[e * DFF + col];
#pragma unroll
    for (int i = 0; i < 4; ++i)
#pragma unroll
      for (int r = 0; r < 4; ++r) {
        if (trow[i][r] < 0) continue;
        float v = acc[i][j][r] + b;
        v = v > 0.f ? v : 0.f;
        v *= wrow[i][r];
        u16* dst = &moe[(size_t)trow[i][r] * DFF + col];
        if (SLOT1) v += bf2f(*dst);
        *dst = f2bf(v);
      }
  }
}

// ---------------- head GEMM: 256^2 tile, 2-phase (2 barriers/K-tile) ----------------
// Mechanism: R4->R6 showed each removed barrier saves ~280 cyc/tile. This merges
// R6's 4 phases into 2 (32 MFMA each) with ONE af and ONE bfl/bfh register set
// (post-MFMA pre-reads reuse dead regs via register WAR ordering).
//   Phase A(t): stage A(t+1)h1 -> an ; MFMA af0(t)x{bfl,bfh} [32] ;
//               post-MFMA pre-read af1(t) <- a_ ; VMCNT(2); SBAR
//   Phase B(t): stage A(t+2)h0,B(t+2)h0,B(t+2)h1 -> a_/b_ ; MFMA af1(t)x{bfl,bfh};
//               post-MFMA pre-read af0(t+1)<-an, bfl/bfh(t+1)<-bn ; VMCNT(6); SBAR
// Rigor (write-after-read, all slots): region's last ds_read is lgkm-drained by
// the MFMA that consumes it, and >=1 barrier separates that drain from the
// overwriting stage-issue: A(t)h1 read@A(t-1),drained pre-B(t-1)-MFMA,+barrier ->
// staged A(t) OK; A(t)h0/B(t)h0/h1 read@B(t-1), drained pre-A(t)-MFMA, +barrier ->
// staged B(t) OK.
// vmcnt ledger (2 loads/slot, steady outstanding 8): A(t)-end: [B(t-1):
// A(t+1)h0,B(t+1)h0,B(t+1)h1 (6)][A(t): A(t+1)h1 (2)] -> VMCNT(2) drains the 6
// needed by B(t)'s pre-reads. B(t)-end: [A(t+1)h1 (2)][B(t): t+2 slots (6)] ->
// VMCNT(6) drains A(t+1)h1 needed by A(t+1)'s pre-read (VMCNT(0) when t+2>=NT,
// since no new slots were issued). Each VMCNT precedes its barrier -> cross-wave
// DMA visibility proven. Targets are >=1 phase old -> no hot stalls.
__device__ __forceinline__ short8 frag(const u16* buf, int row, int kc) {
  return *(const short8*)(buf + (row * 8 + (kc ^ (row & 7))) * 8);
}

__global__ __launch_bounds__(512, 2) void k_head(
    const u16* __restrict__ A, const u16* __restrict__ BT,
    const float* __restrict__ bias, float* __restrict__ C)
{
  __shared__ u16 aL[2][256 * 64];
  __shared__ u16 bL[2][256 * 64];
  const int tid = threadIdx.x;
  const int lane = tid & 63, wave = tid >> 6;
  const int wm = wave >> 2, wn = wave & 3;         // 2 x 4 wave grid
  const int kg = lane >> 4, fr = lane & 15;
  const int wg = (int)blockIdx.x;
  const int swz = (wg & 7) * 250 + (wg >> 3);      // bijective XCD swizzle (2000=8*250)
  const int m0 = (swz & 15) * 256;
  const int n0 = (swz >> 4) * 256;
  const int K = DFF, NT = K / 64;                  // 48 tiles

  size_t gAo[2], gBo[2]; int lAo[2], lBo[2];
#pragma unroll
  for (int i = 0; i < 2; ++i) {
    const int c = i * 512 + tid, rl = c >> 3, s = c & 7;
    const int rA = (rl & 63) + ((rl >> 6) << 7);
    const int gsA = s ^ (rA & 7);
    gAo[i] = (size_t)(m0 + rA) * K + gsA * 8;
    lAo[i] = rA * 64 + s * 8;
    const int rB = (rl & 31) + ((rl >> 5) << 6);
    const int gsB = s ^ (rB & 7);
    gBo[i] = (size_t)(n0 + rB) * K + gsB * 8;
    lBo[i] = rB * 64 + s * 8;
  }
  auto stageA = [&](int kb, u16* buf, int h) {
#pragma unroll
    for (int i = 0; i < 2; ++i)
      async_load16(A + gAo[i] + (size_t)(h * 64) * K + kb, buf + lAo[i] + h * 4096);
  };
  auto stageB = [&](int kb, u16* buf, int h) {
#pragma unroll
    for (int i = 0; i < 2; ++i)
      async_load16(BT + gBo[i] + (size_t)(h * 32) * K + kb, buf + lBo[i] + h * 2048);
  };

  f32x4 acc[8][4] = {};
  short8 af[4][2], bfl[2][2], bfh[2][2];

  // prologue: tile0 {Ah0,Ah1,Bh0,Bh1}; then B(-1)-role slots {A(1)h0,B(1)h0,B(1)h1}
  stageA(0, aL[0], 0); stageA(0, aL[0], 1);
  stageB(0, bL[0], 0); stageB(0, bL[0], 1);
  stageA(64, aL[1], 0); stageB(64, bL[1], 0); stageB(64, bL[1], 1);
  VMCNT(6);                                         // drain tile0's 8 (14 -> keep 6)
  SCHEDB();
  SBAR();
  // pre-reads for tile 0 (emulate B(-1)'s post-MFMA reads): af0(0), bfl(0), bfh(0)
#pragma unroll
  for (int mi = 0; mi < 4; ++mi)
#pragma unroll
    for (int kk = 0; kk < 2; ++kk)
      af[mi][kk] = frag(aL[0], wm * 128 + mi * 16 + fr, kk * 4 + kg);
#pragma unroll
  for (int ni = 0; ni < 2; ++ni)
#pragma unroll
    for (int kk = 0; kk < 2; ++kk) {
      bfl[ni][kk] = frag(bL[0], wn * 64 + ni * 16 + fr, kk * 4 + kg);
      bfh[ni][kk] = frag(bL[0], wn * 64 + 32 + ni * 16 + fr, kk * 4 + kg);
    }

  for (int t = 0; t < NT; ++t) {
    const int cur = t & 1;
    const u16* a_ = aL[cur];
    const u16* b_ = bL[cur];
    u16* aw = aL[cur];
    u16* bw = bL[cur];
    u16* an = aL[cur ^ 1];
    const u16* bn = bL[cur ^ 1];
    const int kb1 = (t + 1) * 64, kb2 = (t + 2) * 64;

    // ======== Phase A: MFMA af0(t) x {bfl,bfh}; stage A(t+1)h1; pre-read af1(t) ========
    if (t + 1 < NT) stageA(kb1, an, 1);
    __builtin_amdgcn_s_setprio(1);
#pragma unroll
    for (int mi = 0; mi < 4; ++mi)
#pragma unroll
      for (int ni = 0; ni < 2; ++ni)
#pragma unroll
        for (int kk = 0; kk < 2; ++kk) {
          acc[mi][ni]     = __builtin_amdgcn_mfma_f32_16x16x32_bf16(af[mi][kk], bfl[ni][kk], acc[mi][ni], 0, 0, 0);
          acc[mi][ni + 2] = __builtin_amdgcn_mfma_f32_16x16x32_bf16(af[mi][kk], bfh[ni][kk], acc[mi][ni + 2], 0, 0, 0);
        }
    __builtin_amdgcn_s_setprio(0);
    // post-MFMA pre-read af1(t) into af (register WAR orders after MFMA reads)
#pragma unroll
    for (int mi = 0; mi < 4; ++mi)
#pragma unroll
      for (int kk = 0; kk < 2; ++kk)
        af[mi][kk] = frag(a_, wm * 128 + 64 + mi * 16 + fr, kk * 4 + kg);
    if (t + 1 < NT) { VMCNT(2); SCHEDB(); }   // drain B(t-1)'s 3 slots for B(t)'s pre-reads
    SBAR();

    // ======== Phase B: MFMA af1(t) x {bfl,bfh}; stage t+2 slots; pre-read tile t+1 ========
    if (t + 2 < NT) { stageA(kb2, aw, 0); stageB(kb2, bw, 0); stageB(kb2, bw, 1); }
    __builtin_amdgcn_s_setprio(1);
#pragma unroll
    for (int mi = 0; mi < 4; ++mi)
#pragma unroll
      for (int ni = 0; ni < 2; ++ni)
#pragma unroll
        for (int kk = 0; kk < 2; ++kk) {
          acc[mi + 4][ni]     = __builtin_amdgcn_mfma_f32_16x16x32_bf16(af[mi][kk], bfl[ni][kk], acc[mi + 4][ni], 0, 0, 0);
          acc[mi + 4][ni + 2] = __builtin_amdgcn_mfma_f32_16x16x32_bf16(af[mi][kk], bfh[ni][kk], acc[mi + 4][ni + 2], 0, 0, 0);
        }
    __builtin_amdgcn_s_setprio(0);
    if (t + 1 < NT) {
      // post-MFMA pre-reads for tile t+1 (regions guaranteed by VMCNT(2)+SBAR above)
#pragma unroll
      for (int mi = 0; mi < 4; ++mi)
#pragma unroll
        for (int kk = 0; kk < 2; ++kk)
          af[mi][kk] = frag(an, wm * 128 + mi * 16 + fr, kk * 4 + kg);
#pragma unroll
      for (int ni = 0; ni < 2; ++ni)
#pragma unroll
        for (int kk = 0; kk < 2; ++kk) {
          bfl[ni][kk] = frag(bn, wn * 64 + ni * 16 + fr, kk * 4 + kg);
          bfh[ni][kk] = frag(bn, wn * 64 + 32 + ni * 16 + fr, kk * 4 + kg);
        }
      if (t + 2 < NT) { VMCNT(6); } else { VMCNT(0); }   // drain A(t+1)h1 for A(t+1)'s pre-read
      SCHEDB();
    }
    SBAR();
  }

  // epilogue: non-temporal stores
#pragma unroll
  for (int ni = 0; ni < 4; ++ni) {
    const int col = n0 + wn * 64 + ni * 16 + fr;
    const float b = bias[col];
#pragma unroll
    for (int mi = 0; mi < 8; ++mi) {
      const int row = m0 + wm * 128 + (mi >> 2) * 64 + (mi & 3) * 16 + kg * 4;
#pragma unroll
      for (int r = 0; r < 4; ++r)
        __builtin_nontemporal_store(acc[mi][ni][r] + b,
                                    &C[(size_t)(row + r) * NVOCAB + col]);
    }
  }
}

extern "C" void kernel_launch(void* const* d_in, const int* in_sizes, int n_in,
                              void* d_out, int out_size, void* d_ws, size_t ws_size,
                              hipStream_t stream) {
  const int*   x     = (const int*)d_in[0];
  const float* emb   = (const float*)d_in[1];
  const float* gw    = (const float*)d_in[2];
  const float* gb    = (const float*)d_in[3];
  const float* expw  = (const float*)d_in[4];
  const float* expb  = (const float*)d_in[5];
  const float* headw = (const float*)d_in[6];
  const float* headb = (const float*)d_in[7];
  float* out = (float*)d_out;

  char* ws = (char*)d_ws;
  size_t off = 0;
  auto alloc = [&](size_t bytes) { size_t r = off; off += (bytes + 255) & ~(size_t)255; return r; };
  u16*   tbf    = (u16*)(ws + alloc((size_t)T_TOKENS * DMODEL * 2));
  int*   counts = (int*)(ws + alloc(2 * NEXP * 4));
  int*   tlist  = (int*)(ws + alloc((size_t)2 * NEXP * T_TOKENS * 4));
  float* wlist  = (float*)(ws + alloc((size_t)2 * NEXP * T_TOKENS * 4));
  u16*   expwT  = (u16*)(ws + alloc((size_t)NEXP * DFF * DMODEL * 2));
  u16*   headwT = (u16*)(ws + alloc((size_t)NVOCAB * DFF * 2));
  u16*   moe    = (u16*)(ws + alloc((size_t)T_TOKENS * DFF * 2));

  hipMemsetAsync(counts, 0, 2 * NEXP * 4, stream);
  k_embed_router<<<T_TOKENS, 256, 0, stream>>>(x, emb, gw, gb, tbf, counts, tlist, wlist);
  k_transpose_cvt<<<dim3(DFF / 32, DMODEL / 32, NEXP), 256, 0, stream>>>(expw, expwT, DMODEL, DFF);
  k_transpose_cvt<<<dim3(NVOCAB / 32, DFF / 32, 1), 256, 0, stream>>>(headw, headwT, DFF, NVOCAB);
  k_ffn_slot<0><<<dim3(DFF / 128, T_TOKENS / 128, NEXP), 256, 0, stream>>>(
      tbf, expwT, expb, counts, tlist, wlist, moe);
  k_ffn_slot<1><<<dim3(DFF / 128, T_TOKENS / 128, NEXP), 256, 0, stream>>>(
      tbf, expwT, expb, counts, tlist, wlist, moe);
  k_head<<<(T_TOKENS / 256) * (NVOCAB / 256), 512, 0, stream>>>(moe, headwT, headb, out);
}

// Round 13
// 1166.520 us; speedup vs baseline: 1.6144x; 1.0125x over previous
//
#include <hip/hip_runtime.h>

typedef unsigned short u16;
typedef __attribute__((ext_vector_type(8))) short short8;
typedef __attribute__((ext_vector_type(4))) float f32x4;

#define T_TOKENS 4096
#define DMODEL   768
#define DFF      3072
#define NEXP     8
#define NVOCAB   32000

__device__ __forceinline__ u16 f2bf(float f) {
  unsigned u = __float_as_uint(f);
  u += 0x7FFFu + ((u >> 16) & 1u);
  return (u16)(u >> 16);
}
__device__ __forceinline__ float bf2f(u16 b) {
  return __uint_as_float(((unsigned)b) << 16);
}

__device__ __forceinline__ void async_load16(const void* g, void* lds) {
  __builtin_amdgcn_global_load_lds((const __attribute__((address_space(1))) void*)g,
                                   (__attribute__((address_space(3))) void*)lds, 16, 0, 0);
}

#define SBAR() __builtin_amdgcn_s_barrier()
#define VMCNT(n) asm volatile("s_waitcnt vmcnt(" #n ")")
#define SCHEDB() __builtin_amdgcn_sched_barrier(0)

__device__ __forceinline__ short8 frag(const u16* buf, int row, int kc) {
  return *(const short8*)(buf + (row * 8 + (kc ^ (row & 7))) * 8);
}

// ---------------- embed + router + top2 list build ----------------
__global__ __launch_bounds__(256) void k_embed_router(
    const int* __restrict__ x, const float* __restrict__ emb,
    const float* __restrict__ gw, const float* __restrict__ gb,
    u16* __restrict__ tbf, int* __restrict__ counts,
    int* __restrict__ tlist, float* __restrict__ wlist)
{
  __shared__ float partial[4][NEXP];
  const int t = blockIdx.x;
  const int tok = x[t];
  const float* er = emb + (size_t)tok * DMODEL;
  float p[NEXP];
#pragma unroll
  for (int e = 0; e < NEXP; ++e) p[e] = 0.f;
#pragma unroll
  for (int i = 0; i < 3; ++i) {
    const int d = threadIdx.x + i * 256;
    const float v = er[d];
    tbf[(size_t)t * DMODEL + d] = f2bf(v);
#pragma unroll
    for (int e = 0; e < NEXP; ++e) p[e] += v * gw[d * NEXP + e];
  }
#pragma unroll
  for (int e = 0; e < NEXP; ++e)
#pragma unroll
    for (int m = 32; m >= 1; m >>= 1) p[e] += __shfl_xor(p[e], m);
  const int lane = threadIdx.x & 63, wv = threadIdx.x >> 6;
  if (lane == 0)
    for (int e = 0; e < NEXP; ++e) partial[wv][e] = p[e];
  __syncthreads();
  if (threadIdx.x == 0) {
    float l[NEXP];
    for (int e = 0; e < NEXP; ++e)
      l[e] = partial[0][e] + partial[1][e] + partial[2][e] + partial[3][e] + gb[e];
    int i0 = 0;
    for (int e = 1; e < NEXP; ++e) if (l[e] > l[i0]) i0 = e;   // ties: first (jax)
    int i1 = -1;
    for (int e = 0; e < NEXP; ++e) { if (e == i0) continue; if (i1 < 0 || l[e] > l[i1]) i1 = e; }
    const float w0 = 1.f / (1.f + expf(l[i1] - l[i0]));
    int p0 = atomicAdd(&counts[0 * NEXP + i0], 1);
    tlist[(0 * NEXP + i0) * T_TOKENS + p0] = t;
    wlist[(0 * NEXP + i0) * T_TOKENS + p0] = w0;
    int p1 = atomicAdd(&counts[1 * NEXP + i1], 1);
    tlist[(1 * NEXP + i1) * T_TOKENS + p1] = t;
    wlist[(1 * NEXP + i1) * T_TOKENS + p1] = 1.f - w0;
  }
}

// ---------------- transpose + fp32->bf16 convert (64x64 tile, u32 stores) ----------------
// Store phase packs 2 consecutive-R bf16 per u32 -> 128B contiguous runs per
// 32 lanes (vs 64B scalar before). LDS stride 65: store-read bank = (2h+ccl)%32,
// 2-way aliasing only (free, m136).
__global__ __launch_bounds__(256) void k_transpose_cvt(
    const float* __restrict__ src, u16* __restrict__ dst, int R, int C)
{
  __shared__ float tile[64][65];
  const float* s = src + (size_t)blockIdx.z * R * C;
  u16* d = dst + (size_t)blockIdx.z * R * C;
  const int tx = threadIdx.x & 63, ty = threadIdx.x >> 6;   // ty 0..3
  const int c = blockIdx.x * 64 + tx;
#pragma unroll
  for (int i = 0; i < 16; ++i) {
    const int r = blockIdx.y * 64 + ty + i * 4;
    tile[ty + i * 4][tx] = s[(size_t)r * C + c];
  }
  __syncthreads();
  const int h = threadIdx.x & 31, v = threadIdx.x >> 5;     // v 0..7
  const int rr = blockIdx.y * 64 + h * 2;
#pragma unroll
  for (int i = 0; i < 8; ++i) {
    const int ccl = v + i * 8;
    const int cc = blockIdx.x * 64 + ccl;
    const unsigned lo = f2bf(tile[h * 2][ccl]);
    const unsigned hi = f2bf(tile[h * 2 + 1][ccl]);
    *(unsigned*)&d[(size_t)cc * R + rr] = lo | (hi << 16);
  }
}

// ---------------- sparse MoE FFN: R12-style 2-phase pipelined gather-GEMM ----------------
// 128^2 tile, 4 waves (2x2 of 64x64), K=768 (NT=12), LDS 64KB -> 2 blocks/CU.
// Slots (64 rows, 2 loads/thread): h0 = rows {0-31}u{64-95}, h1 = {32-63}u{96-127}
// so afA(i=0,1) reads A-h0, afB(i=2,3) reads A-h1, bf spans B-h0+h1 (per wave).
// Phase A(t): stage A(t+1)h1 -> an; MFMA afA x bf [16]; post-read afB(t) from
//             A(t)h1 (staged @A(t-1), guarded VMCNT(6)@B(t-1)+SBAR); VMCNT(2); SBAR
// Phase B(t): stage A(t+2)h0,B(t+2)h0,B(t+2)h1 -> aw/bw; MFMA afB x bf [16];
//             post-read afA/bf(t+1) from A(t+1)h0,B(t+1)h0,h1 (staged @B(t-1),
//             guarded VMCNT(2)@A(t)+SBAR); VMCNT(6) [or (0) at t==NT-2]; SBAR
// vmcnt ledger (2 loads/slot): A(t)-end outstanding = B(t-1)'s 6 + A(t)'s 2 = 8
// -> VMCNT(2) drains B(t-1)'s slots. B(t)-end = A(t+1)h1's 2 + B(t)'s 6 = 8 ->
// VMCNT(6) drains A(t+1)h1. WAR: every overwritten region's last read was
// lgkm-drained by its consuming MFMA one phase earlier + barrier between.
template <int SLOT1>
__global__ __launch_bounds__(256) void k_ffn_slot(
    const u16* __restrict__ tbf, const u16* __restrict__ BT,
    const float* __restrict__ eb, const int* __restrict__ counts,
    const int* __restrict__ tlist, const float* __restrict__ wlist,
    u16* __restrict__ moe)
{
  const int e = blockIdx.z;
  const int cnt = counts[SLOT1 * NEXP + e];
  const int mb = blockIdx.y;
  if (mb * 128 >= cnt) return;
  const int base = (SLOT1 * NEXP + e) * T_TOKENS + mb * 128;
  const int lim = cnt - mb * 128;

  __shared__ u16 aT[2][128 * 64];
  __shared__ u16 bT[2][128 * 64];
  const int tid = threadIdx.x;
  const int wave = tid >> 6, lane = tid & 63;
  const int wm = wave >> 1, wn = wave & 1;
  const int kg = lane >> 4, fr = lane & 15;
  const int n0 = blockIdx.x * 128;
  const u16* Be = BT + (size_t)e * DFF * DMODEL;
  const int K = DMODEL, NT = K / 64;              // 12 K-tiles

  // hoisted staging descriptors (2 chunks/thread per slot)
  int gs8[2], lOf[2]; size_t gBo[2]; int tokA[2][2];
#pragma unroll
  for (int i = 0; i < 2; ++i) {
    const int cch = i * 256 + tid, rl = cch >> 3, sft = cch & 7;
    const int rb = (rl & 31) + ((rl >> 5) << 6);  // slot row base (h adds 32)
    gs8[i] = (sft ^ (rl & 7)) * 8;                // pre-swizzled source slot
    lOf[i] = rb * 64 + sft * 8;                   // linear LDS dest (u16 units)
    gBo[i] = (size_t)(n0 + rb) * K + gs8[i];
#pragma unroll
    for (int hh = 0; hh < 2; ++hh) {
      const int row = rb + hh * 32;
      tokA[i][hh] = tlist[base + (row < lim ? row : lim - 1)];
    }
  }
  auto stageA = [&](int kb, u16* buf, int h) {
#pragma unroll
    for (int i = 0; i < 2; ++i)
      async_load16(tbf + (size_t)tokA[i][h] * K + kb + gs8[i], buf + lOf[i] + h * 2048);
  };
  auto stageB = [&](int kb, u16* buf, int h) {
#pragma unroll
    for (int i = 0; i < 2; ++i)
      async_load16(Be + gBo[i] + (size_t)(h * 32) * K + kb, buf + lOf[i] + h * 2048);
  };

  f32x4 acc[4][4] = {};
  short8 afA[2][2], afB[2][2], bf[4][2];

  // prologue: tile0 all 4 slots + B(-1)-role {A(1)h0,B(1)h0,B(1)h1}
  stageA(0, aT[0], 0); stageA(0, aT[0], 1);
  stageB(0, bT[0], 0); stageB(0, bT[0], 1);
  stageA(64, aT[1], 0); stageB(64, bT[1], 0); stageB(64, bT[1], 1);
  VMCNT(6); SCHEDB(); SBAR();
#pragma unroll
  for (int i = 0; i < 2; ++i)
#pragma unroll
    for (int kk = 0; kk < 2; ++kk)
      afA[i][kk] = frag(aT[0], wm * 64 + i * 16 + fr, kk * 4 + kg);
#pragma unroll
  for (int j = 0; j < 4; ++j)
#pragma unroll
    for (int kk = 0; kk < 2; ++kk)
      bf[j][kk] = frag(bT[0], wn * 64 + j * 16 + fr, kk * 4 + kg);

  for (int t = 0; t < NT; ++t) {
    const int cur = t & 1;
    const u16* a_ = aT[cur];
    u16* aw = aT[cur]; u16* bw = bT[cur];
    u16* an = aT[cur ^ 1]; const u16* bn = bT[cur ^ 1];
    const int kb1 = (t + 1) * 64, kb2 = (t + 2) * 64;

    // ---- Phase A ----
    if (t + 1 < NT) stageA(kb1, an, 1);
    __builtin_amdgcn_s_setprio(1);
#pragma unroll
    for (int i = 0; i < 2; ++i)
#pragma unroll
      for (int j = 0; j < 4; ++j)
#pragma unroll
        for (int kk = 0; kk < 2; ++kk)
          acc[i][j] = __builtin_amdgcn_mfma_f32_16x16x32_bf16(afA[i][kk], bf[j][kk], acc[i][j], 0, 0, 0);
    __builtin_amdgcn_s_setprio(0);
#pragma unroll
    for (int i = 0; i < 2; ++i)
#pragma unroll
      for (int kk = 0; kk < 2; ++kk)
        afB[i][kk] = frag(a_, wm * 64 + 32 + i * 16 + fr, kk * 4 + kg);
    if (t + 1 < NT) { VMCNT(2); SCHEDB(); }
    SBAR();

    // ---- Phase B ----
    if (t + 2 < NT) { stageA(kb2, aw, 0); stageB(kb2, bw, 0); stageB(kb2, bw, 1); }
    __builtin_amdgcn_s_setprio(1);
#pragma unroll
    for (int i = 0; i < 2; ++i)
#pragma unroll
      for (int j = 0; j < 4; ++j)
#pragma unroll
        for (int kk = 0; kk < 2; ++kk)
          acc[i + 2][j] = __builtin_amdgcn_mfma_f32_16x16x32_bf16(afB[i][kk], bf[j][kk], acc[i + 2][j], 0, 0, 0);
    __builtin_amdgcn_s_setprio(0);
    if (t + 1 < NT) {
#pragma unroll
      for (int i = 0; i < 2; ++i)
#pragma unroll
        for (int kk = 0; kk < 2; ++kk)
          afA[i][kk] = frag(an, wm * 64 + i * 16 + fr, kk * 4 + kg);
#pragma unroll
      for (int j = 0; j < 4; ++j)
#pragma unroll
        for (int kk = 0; kk < 2; ++kk)
          bf[j][kk] = frag(bn, wn * 64 + j * 16 + fr, kk * 4 + kg);
      if (t + 2 < NT) { VMCNT(6); } else { VMCNT(0); }
      SCHEDB();
    }
    SBAR();
  }

  // epilogue: per-row token/weight lookup, relu+bias, weighted (add for slot1)
  int trow[4][4]; float wrow[4][4];
#pragma unroll
  for (int i = 0; i < 4; ++i)
#pragma unroll
    for (int r = 0; r < 4; ++r) {
      const int row = wm * 64 + i * 16 + kg * 4 + r;
      if (row < lim) { trow[i][r] = tlist[base + row]; wrow[i][r] = wlist[base + row]; }
      else trow[i][r] = -1;
    }
#pragma unroll
  for (int j = 0; j < 4; ++j) {
    const int col = n0 + wn * 64 + j * 16 + fr;
    const float b = eb[e * DFF + col];
#pragma unroll
    for (int i = 0; i < 4; ++i)
#pragma unroll
      for (int r = 0; r < 4; ++r) {
        if (trow[i][r] < 0) continue;
        float v = acc[i][j][r] + b;
        v = v > 0.f ? v : 0.f;
        v *= wrow[i][r];
        u16* dst = &moe[(size_t)trow[i][r] * DFF + col];
        if (SLOT1) v += bf2f(*dst);
        *dst = f2bf(v);
      }
  }
}

// ---------------- head GEMM: 256^2 tile, 2-phase (R12, best verified) ----------------
__global__ __launch_bounds__(512, 2) void k_head(
    const u16* __restrict__ A, const u16* __restrict__ BT,
    const float* __restrict__ bias, float* __restrict__ C)
{
  __shared__ u16 aL[2][256 * 64];
  __shared__ u16 bL[2][256 * 64];
  const int tid = threadIdx.x;
  const int lane = tid & 63, wave = tid >> 6;
  const int wm = wave >> 2, wn = wave & 3;         // 2 x 4 wave grid
  const int kg = lane >> 4, fr = lane & 15;
  const int wg = (int)blockIdx.x;
  const int swz = (wg & 7) * 250 + (wg >> 3);      // bijective XCD swizzle (2000=8*250)
  const int m0 = (swz & 15) * 256;
  const int n0 = (swz >> 4) * 256;
  const int K = DFF, NT = K / 64;                  // 48 tiles

  size_t gAo[2], gBo[2]; int lAo[2], lBo[2];
#pragma unroll
  for (int i = 0; i < 2; ++i) {
    const int c = i * 512 + tid, rl = c >> 3, s = c & 7;
    const int rA = (rl & 63) + ((rl >> 6) << 7);
    const int gsA = s ^ (rA & 7);
    gAo[i] = (size_t)(m0 + rA) * K + gsA * 8;
    lAo[i] = rA * 64 + s * 8;
    const int rB = (rl & 31) + ((rl >> 5) << 6);
    const int gsB = s ^ (rB & 7);
    gBo[i] = (size_t)(n0 + rB) * K + gsB * 8;
    lBo[i] = rB * 64 + s * 8;
  }
  auto stageA = [&](int kb, u16* buf, int h) {
#pragma unroll
    for (int i = 0; i < 2; ++i)
      async_load16(A + gAo[i] + (size_t)(h * 64) * K + kb, buf + lAo[i] + h * 4096);
  };
  auto stageB = [&](int kb, u16* buf, int h) {
#pragma unroll
    for (int i = 0; i < 2; ++i)
      async_load16(BT + gBo[i] + (size_t)(h * 32) * K + kb, buf + lBo[i] + h * 2048);
  };

  f32x4 acc[8][4] = {};
  short8 af[4][2], bfl[2][2], bfh[2][2];

  stageA(0, aL[0], 0); stageA(0, aL[0], 1);
  stageB(0, bL[0], 0); stageB(0, bL[0], 1);
  stageA(64, aL[1], 0); stageB(64, bL[1], 0); stageB(64, bL[1], 1);
  VMCNT(6);
  SCHEDB();
  SBAR();
#pragma unroll
  for (int mi = 0; mi < 4; ++mi)
#pragma unroll
    for (int kk = 0; kk < 2; ++kk)
      af[mi][kk] = frag(aL[0], wm * 128 + mi * 16 + fr, kk * 4 + kg);
#pragma unroll
  for (int ni = 0; ni < 2; ++ni)
#pragma unroll
    for (int kk = 0; kk < 2; ++kk) {
      bfl[ni][kk] = frag(bL[0], wn * 64 + ni * 16 + fr, kk * 4 + kg);
      bfh[ni][kk] = frag(bL[0], wn * 64 + 32 + ni * 16 + fr, kk * 4 + kg);
    }

  for (int t = 0; t < NT; ++t) {
    const int cur = t & 1;
    const u16* a_ = aL[cur];
    u16* aw = aL[cur];
    u16* bw = bL[cur];
    u16* an = aL[cur ^ 1];
    const u16* bn = bL[cur ^ 1];
    const int kb1 = (t + 1) * 64, kb2 = (t + 2) * 64;

    // ======== Phase A ========
    if (t + 1 < NT) stageA(kb1, an, 1);
    __builtin_amdgcn_s_setprio(1);
#pragma unroll
    for (int mi = 0; mi < 4; ++mi)
#pragma unroll
      for (int ni = 0; ni < 2; ++ni)
#pragma unroll
        for (int kk = 0; kk < 2; ++kk) {
          acc[mi][ni]     = __builtin_amdgcn_mfma_f32_16x16x32_bf16(af[mi][kk], bfl[ni][kk], acc[mi][ni], 0, 0, 0);
          acc[mi][ni + 2] = __builtin_amdgcn_mfma_f32_16x16x32_bf16(af[mi][kk], bfh[ni][kk], acc[mi][ni + 2], 0, 0, 0);
        }
    __builtin_amdgcn_s_setprio(0);
#pragma unroll
    for (int mi = 0; mi < 4; ++mi)
#pragma unroll
      for (int kk = 0; kk < 2; ++kk)
        af[mi][kk] = frag(a_, wm * 128 + 64 + mi * 16 + fr, kk * 4 + kg);
    if (t + 1 < NT) { VMCNT(2); SCHEDB(); }
    SBAR();

    // ======== Phase B ========
    if (t + 2 < NT) { stageA(kb2, aw, 0); stageB(kb2, bw, 0); stageB(kb2, bw, 1); }
    __builtin_amdgcn_s_setprio(1);
#pragma unroll
    for (int mi = 0; mi < 4; ++mi)
#pragma unroll
      for (int ni = 0; ni < 2; ++ni)
#pragma unroll
        for (int kk = 0; kk < 2; ++kk) {
          acc[mi + 4][ni]     = __builtin_amdgcn_mfma_f32_16x16x32_bf16(af[mi][kk], bfl[ni][kk], acc[mi + 4][ni], 0, 0, 0);
          acc[mi + 4][ni + 2] = __builtin_amdgcn_mfma_f32_16x16x32_bf16(af[mi][kk], bfh[ni][kk], acc[mi + 4][ni + 2], 0, 0, 0);
        }
    __builtin_amdgcn_s_setprio(0);
    if (t + 1 < NT) {
#pragma unroll
      for (int mi = 0; mi < 4; ++mi)
#pragma unroll
        for (int kk = 0; kk < 2; ++kk)
          af[mi][kk] = frag(an, wm * 128 + mi * 16 + fr, kk * 4 + kg);
#pragma unroll
      for (int ni = 0; ni < 2; ++ni)
#pragma unroll
        for (int kk = 0; kk < 2; ++kk) {
          bfl[ni][kk] = frag(bn, wn * 64 + ni * 16 + fr, kk * 4 + kg);
          bfh[ni][kk] = frag(bn, wn * 64 + 32 + ni * 16 + fr, kk * 4 + kg);
        }
      if (t + 2 < NT) { VMCNT(6); } else { VMCNT(0); }
      SCHEDB();
    }
    SBAR();
  }

  // epilogue: non-temporal stores
#pragma unroll
  for (int ni = 0; ni < 4; ++ni) {
    const int col = n0 + wn * 64 + ni * 16 + fr;
    const float b = bias[col];
#pragma unroll
    for (int mi = 0; mi < 8; ++mi) {
      const int row = m0 + wm * 128 + (mi >> 2) * 64 + (mi & 3) * 16 + kg * 4;
#pragma unroll
      for (int r = 0; r < 4; ++r)
        __builtin_nontemporal_store(acc[mi][ni][r] + b,
                                    &C[(size_t)(row + r) * NVOCAB + col]);
    }
  }
}

extern "C" void kernel_launch(void* const* d_in, const int* in_sizes, int n_in,
                              void* d_out, int out_size, void* d_ws, size_t ws_size,
                              hipStream_t stream) {
  const int*   x     = (const int*)d_in[0];
  const float* emb   = (const float*)d_in[1];
  const float* gw    = (const float*)d_in[2];
  const float* gb    = (const float*)d_in[3];
  const float* expw  = (const float*)d_in[4];
  const float* expb  = (const float*)d_in[5];
  const float* headw = (const float*)d_in[6];
  const float* headb = (const float*)d_in[7];
  float* out = (float*)d_out;

  char* ws = (char*)d_ws;
  size_t off = 0;
  auto alloc = [&](size_t bytes) { size_t r = off; off += (bytes + 255) & ~(size_t)255; return r; };
  u16*   tbf    = (u16*)(ws + alloc((size_t)T_TOKENS * DMODEL * 2));
  int*   counts = (int*)(ws + alloc(2 * NEXP * 4));
  int*   tlist  = (int*)(ws + alloc((size_t)2 * NEXP * T_TOKENS * 4));
  float* wlist  = (float*)(ws + alloc((size_t)2 * NEXP * T_TOKENS * 4));
  u16*   expwT  = (u16*)(ws + alloc((size_t)NEXP * DFF * DMODEL * 2));
  u16*   headwT = (u16*)(ws + alloc((size_t)NVOCAB * DFF * 2));
  u16*   moe    = (u16*)(ws + alloc((size_t)T_TOKENS * DFF * 2));

  hipMemsetAsync(counts, 0, 2 * NEXP * 4, stream);
  k_embed_router<<<T_TOKENS, 256, 0, stream>>>(x, emb, gw, gb, tbf, counts, tlist, wlist);
  k_transpose_cvt<<<dim3(DFF / 64, DMODEL / 64, NEXP), 256, 0, stream>>>(expw, expwT, DMODEL, DFF);
  k_transpose_cvt<<<dim3(NVOCAB / 64, DFF / 64, 1), 256, 0, stream>>>(headw, headwT, DFF, NVOCAB);
  k_ffn_slot<0><<<dim3(DFF / 128, T_TOKENS / 128, NEXP), 256, 0, stream>>>(
      tbf, expwT, expb, counts, tlist, wlist, moe);
  k_ffn_slot<1><<<dim3(DFF / 128, T_TOKENS / 128, NEXP), 256, 0, stream>>>(
      tbf, expwT, expb, counts, tlist, wlist, moe);
  k_head<<<(T_TOKENS / 256) * (NVOCAB / 256), 512, 0, stream>>>(moe, headwT, headb, out);
}